// Round 10
// baseline (1462.995 us; speedup 1.0000x reference)
//
#include <hip/hip_runtime.h>
#include <cstdint>
#include <cstddef>

#define NN 32
#define NODE_ELEMS 1605632  // 8*56*56*64 elements per slot (NHWC); bf16 storage

typedef unsigned __int128 u128;

// ---------------- host: replicate np.random.default_rng(0).random((32,32)) < 0.25 ----
static void compute_adj(bool adj[NN][NN]) {
  uint32_t pool[4];
  uint32_t hc = 0x43b0d7e5u;
  auto hashmix = [&hc](uint32_t v) -> uint32_t {
    v ^= hc; hc *= 0x931e8875u; v *= hc; v ^= v >> 16; return v;
  };
  auto mix = [](uint32_t x, uint32_t y) -> uint32_t {
    uint32_t r = x * 0xca01f9ddu - y * 0x4973f715u; r ^= r >> 16; return r;
  };
  for (int i = 0; i < 4; i++) pool[i] = hashmix(0u);
  for (int s = 0; s < 4; s++)
    for (int d = 0; d < 4; d++)
      if (s != d) pool[d] = mix(pool[d], hashmix(pool[s]));
  uint32_t hb = 0x8b51f9ddu;
  uint32_t w[8];
  for (int k = 0; k < 8; k++) {
    uint32_t v = pool[k & 3];
    v ^= hb; hb *= 0x58f38dedu; v *= hb; v ^= v >> 16;
    w[k] = v;
  }
  uint64_t s64[4];
  for (int j = 0; j < 4; j++) s64[j] = (uint64_t)w[2 * j] | ((uint64_t)w[2 * j + 1] << 32);
  u128 initstate = ((u128)s64[0] << 64) | s64[1];
  u128 initseq   = ((u128)s64[2] << 64) | s64[3];
  const u128 MULT = ((u128)0x2360ED051FC65DA4ULL << 64) | 0x4385DF649FCCF645ULL;
  u128 state = 0;
  u128 inc = (initseq << 1) | 1;
  state = state * MULT + inc;
  state += initstate;
  state = state * MULT + inc;
  for (int i = 0; i < NN; i++)
    for (int j = 0; j < NN; j++) {
      state = state * MULT + inc;
      uint64_t hi = (uint64_t)(state >> 64), lo = (uint64_t)state;
      unsigned rot = (unsigned)(hi >> 58);
      uint64_t xr = hi ^ lo;
      uint64_t out = (xr >> rot) | (xr << ((64u - rot) & 63u));
      double dv = (double)(out >> 11) * (1.0 / 9007199254740992.0);
      adj[i][j] = (dv < 0.25);
    }
}

// ---------------- device ----------------
struct NodeDesc {
  uint8_t node, npred, slot, flags;
  uint8_t pred_slot[31];
  uint8_t pad;
};
struct GroupArg { int n; int n8; NodeDesc d[16]; };
struct FinalArg { int nf; uint8_t slot[32]; };

__device__ __forceinline__ float bf2f_lo(unsigned int w) {
  union { unsigned int u; float f; } c; c.u = w << 16; return c.f;
}
__device__ __forceinline__ float bf2f_hi(unsigned int w) {
  union { unsigned int u; float f; } c; c.u = w & 0xFFFF0000u; return c.f;
}
__device__ __forceinline__ float bf2f(unsigned short h) {
  union { unsigned int u; float f; } c; c.u = ((unsigned int)h) << 16; return c.f;
}
__device__ __forceinline__ unsigned short f2bf(float f) {
  union { float f; unsigned int u; } c; c.f = f;
  unsigned int u = c.u + 0x7FFFu + ((c.u >> 16) & 1u);  // RNE
  return (unsigned short)(u >> 16);
}

// Workspace slots are bf16 NHWC: elem(b,y,x,c) = ((b*56+y)*56+x)*64 + c.
// All math fp32; only inter-node storage is bf16.
// 1D grid, linear = tile*n8 + nodeIdx (n8 = group size padded to mult of 8)
// -> linear%8 == node%8: all 392 tiles of a node land on ONE XCD, so pred-slot
// streaming + halo overlap are L2 hits instead of cross-XCD HBM re-fetch
// (R9: one launch fetched 1.4 GB > whole-network ideal 0.6 GB).
// FINAL-mean atomics removed entirely (R9 WRITE=111MB was atomic RMW garbage).
__global__ __launch_bounds__(512) void node_kernel(
    GroupArg g,
    const float* __restrict__ x,
    const float* __restrict__ dwall,
    const float* __restrict__ pwall,
    const float* __restrict__ gmall,
    const float* __restrict__ btall,
    const float* __restrict__ mnall,
    const float* __restrict__ vrall,
    const float* __restrict__ aggw,
    unsigned short* __restrict__ wsb)   // bf16 slots
{
  __shared__ float smem[6400];   // halo [100 pos][64 c]; reused as t[64 pos][64 c]
  __shared__ float pwb[4096];    // swizzled pointwise weights
  __shared__ float wlds[32];

  const int lin = blockIdx.x;
  const int y = lin % g.n8;
  if (y >= g.n) return;          // padding block (uniform exit, pre-barrier)
  const int tl = lin / g.n8;
  const NodeDesc nd = g.d[y];
  const int node = nd.node;
  const int t = threadIdx.x;
  const int b = tl / 49;
  const int tile = tl - b * 49;
  const int ty = (tile / 7) * 8;
  const int tx = (tile % 7) * 8;

  // stage pw weights quad-swizzled: (o,c) -> o*64 + (((c>>2)^((o>>2)&15))<<2)|(c&3)
  {
    const float* pwn = pwall + node * 4096;
    #pragma unroll
    for (int i = 0; i < 8; i++) {
      int gidx = t + 512 * i;
      int o = gidx >> 6, cc = gidx & 63;
      pwb[o * 64 + ((((cc >> 2) ^ ((o >> 2) & 15)) << 2) | (cc & 3))] = pwn[gidx];
    }
  }

  int dwc, pbase;   // depthwise ownership: channel + first of 8 positions
  if (nd.npred == 0) { dwc = t >> 3; pbase = (t & 7) * 8; }   // NCHW x gather layout
  else               { dwc = t & 63; pbase = (t >> 6) * 8; }  // NHWC halo layout

  const float* k9 = dwall + (node * 64 + dwc) * 9;
  float kk[9];
  #pragma unroll
  for (int q = 0; q < 9; q++) kk[q] = k9[q];

  float tv[8];

  if (nd.npred == 0) {
    // input node: depthwise stride-2 over relu(x), x is NCHW [8][64][112][112] fp32
    const float* xb = x + (size_t)(b * 64 + dwc) * 12544;
    #pragma unroll
    for (int j = 0; j < 8; j++) {
      int p = pbase + j;
      int oy = ty + (p >> 3), ox = tx + (p & 7);
      int iy0 = oy * 2 - 1, ix0 = ox * 2 - 1;
      float s = 0.f;
      #pragma unroll
      for (int dy = 0; dy < 3; dy++) {
        int iy = iy0 + dy;
        if ((unsigned)iy >= 112u) continue;
        const float* row = xb + iy * 112;
        #pragma unroll
        for (int dx = 0; dx < 3; dx++) {
          int ix = ix0 + dx;
          if ((unsigned)ix >= 112u) continue;
          s += fmaxf(row[ix], 0.f) * kk[dy * 3 + dx];
        }
      }
      tv[j] = s;
    }
    __syncthreads();  // match else-branch barrier count (wlds)
    __syncthreads();  // (halo build)
    __syncthreads();  // (halo consume)
  } else {
    // sigmoid weights only for >=2 preds (single pred = pass-through)
    if (t < nd.npred) {
      float wv = 1.f / (1.f + expf(-aggw[node * 32 + t]));
      wlds[t] = (nd.npred == 1) ? 1.0f : wv;
    }
    __syncthreads();
    const int np = nd.npred;
    // aggregate + relu into fp32 NHWC halo from bf16 slots.
    // 800 units of 8 channels (16 B); thread owns unit t and 512+t (t<288);
    // 2 independent acc chains -> 2*np loads in flight.
    {
      float sa[2][8];
      int off[2];
      bool inb[2];
      #pragma unroll
      for (int u = 0; u < 2; u++) {
        int idx = t + u * 512;
        bool valid = (u == 0) || (t < 288);
        int pos = idx >> 3, q8 = idx & 7;
        int hy = pos / 10, hx = pos - hy * 10;
        int gy = ty + hy - 1, gx = tx + hx - 1;
        inb[u] = valid && ((unsigned)gy < 56u) && ((unsigned)gx < 56u);
        off[u] = ((b * 56 + gy) * 56 + gx) * 64 + q8 * 8;
        #pragma unroll
        for (int k = 0; k < 8; k++) sa[u][k] = 0.f;
      }
      for (int p = 0; p < np; p++) {
        const unsigned short* pb = wsb + (size_t)nd.pred_slot[p] * NODE_ELEMS;
        float wv = wlds[p];
        #pragma unroll
        for (int u = 0; u < 2; u++) {
          if (inb[u]) {
            uint4 v = *(const uint4*)(pb + off[u]);
            sa[u][0] = fmaf(wv, bf2f_lo(v.x), sa[u][0]);
            sa[u][1] = fmaf(wv, bf2f_hi(v.x), sa[u][1]);
            sa[u][2] = fmaf(wv, bf2f_lo(v.y), sa[u][2]);
            sa[u][3] = fmaf(wv, bf2f_hi(v.y), sa[u][3]);
            sa[u][4] = fmaf(wv, bf2f_lo(v.z), sa[u][4]);
            sa[u][5] = fmaf(wv, bf2f_hi(v.z), sa[u][5]);
            sa[u][6] = fmaf(wv, bf2f_lo(v.w), sa[u][6]);
            sa[u][7] = fmaf(wv, bf2f_hi(v.w), sa[u][7]);
          }
        }
      }
      #pragma unroll
      for (int u = 0; u < 2; u++) {
        int idx = t + u * 512;
        if ((u == 0) || (t < 288)) {
          float4 s0 = make_float4(fmaxf(sa[u][0], 0.f), fmaxf(sa[u][1], 0.f),
                                  fmaxf(sa[u][2], 0.f), fmaxf(sa[u][3], 0.f));
          float4 s1 = make_float4(fmaxf(sa[u][4], 0.f), fmaxf(sa[u][5], 0.f),
                                  fmaxf(sa[u][6], 0.f), fmaxf(sa[u][7], 0.f));
          *(float4*)&smem[idx * 8] = s0;
          *(float4*)&smem[idx * 8 + 4] = s1;
        }
      }
    }
    __syncthreads();
    // depthwise 3x3 from NHWC halo: lane = channel -> conflict-free
    #pragma unroll
    for (int j = 0; j < 8; j++) {
      int p = pbase + j;
      int py = p >> 3, px = p & 7;
      const float* r0 = smem + (py * 10 + px) * 64 + dwc;
      tv[j] = r0[0]    * kk[0] + r0[64]   * kk[1] + r0[128]  * kk[2]
            + r0[640]  * kk[3] + r0[704]  * kk[4] + r0[768]  * kk[5]
            + r0[1280] * kk[6] + r0[1344] * kk[7] + r0[1408] * kk[8];
    }
    __syncthreads();  // halo reads done; smem re-purposed as t matrix
  }

  // t matrix t[p][c] quad-swizzled: quad' = (c>>2) ^ ((p>>2)&15)
  #pragma unroll
  for (int j = 0; j < 8; j++) {
    int p = pbase + j;
    smem[p * 64 + (((((dwc >> 2) ^ ((p >> 2) & 15))) << 2) | (dwc & 3))] = tv[j];
  }
  __syncthreads();

  // pointwise 64x64: 4 out-channels x 2 positions per thread (8 acc)
  const int oq = t & 15;          // out-channel quad selector
  const int pgrp = t >> 4;        // position pair selector [0,32)
  const int o0 = oq << 2;
  const int p0 = pgrp << 1;
  const int bswz = (pgrp >> 1) & 15;   // (p>>2) for both p0 and p0+1
  float acc[2][4] = {};           // [pj][oi]
  #pragma unroll 4
  for (int k4 = 0; k4 < 16; k4++) {
    float4 A[4], B[2];
    #pragma unroll
    for (int oi = 0; oi < 4; oi++)
      A[oi] = *(const float4*)&pwb[(o0 + oi) * 64 + ((k4 ^ oq) << 2)];
    #pragma unroll
    for (int pj = 0; pj < 2; pj++)
      B[pj] = *(const float4*)&smem[(p0 + pj) * 64 + ((k4 ^ bswz) << 2)];
    #pragma unroll
    for (int pj = 0; pj < 2; pj++) {
      #pragma unroll
      for (int oi = 0; oi < 4; oi++) {
        acc[pj][oi] = fmaf(A[oi].x, B[pj].x, acc[pj][oi]);
        acc[pj][oi] = fmaf(A[oi].y, B[pj].y, acc[pj][oi]);
        acc[pj][oi] = fmaf(A[oi].z, B[pj].z, acc[pj][oi]);
        acc[pj][oi] = fmaf(A[oi].w, B[pj].w, acc[pj][oi]);
      }
    }
  }

  // BN + bf16 slot store (every node has a slot now; FINAL slots persist)
  float inv[4], mn[4], bt[4];
  #pragma unroll
  for (int oi = 0; oi < 4; oi++) {
    int gi = node * 64 + o0 + oi;
    inv[oi] = gmall[gi] / sqrtf(vrall[gi] + 1e-5f);
    mn[oi] = mnall[gi];
    bt[oi] = btall[gi];
  }
  unsigned short* slotp = wsb + (size_t)nd.slot * NODE_ELEMS;
  #pragma unroll
  for (int pj = 0; pj < 2; pj++) {
    int p = p0 + pj;
    int gy = ty + (p >> 3), gx = tx + (p & 7);
    size_t base = (((size_t)(b * 56 + gy)) * 56 + gx) * 64 + o0;
    ushort4 h;
    h.x = f2bf((acc[pj][0] - mn[0]) * inv[0] + bt[0]);
    h.y = f2bf((acc[pj][1] - mn[1]) * inv[1] + bt[1]);
    h.z = f2bf((acc[pj][2] - mn[2]) * inv[2] + bt[2]);
    h.w = f2bf((acc[pj][3] - mn[3]) * inv[3] + bt[3]);
    *(ushort4*)&slotp[base] = h;
  }
}

// Mean of FINAL bf16 slots (fp32 accumulate) -> NCHW d_out. Block per (b,y) row.
__global__ __launch_bounds__(256) void finalize_kernel(
    FinalArg fa, const unsigned short* __restrict__ wsb,
    float* __restrict__ out, float inv_nf)
{
  __shared__ float lds[57 * 64];
  int by = blockIdx.x;
  int b = by / 56, y = by - b * 56;
  size_t rbase = (((size_t)b * 56 + y) * 56) * 64;  // [x][c]
  for (int i = threadIdx.x; i < 3584; i += 256) {
    float s = 0.f;
    for (int f = 0; f < fa.nf; f++)
      s += bf2f(wsb[(size_t)fa.slot[f] * NODE_ELEMS + rbase + i]);
    int xx = i >> 6, c = i & 63;
    lds[c * 57 + xx] = s * inv_nf;
  }
  __syncthreads();
  float* dst = out + (size_t)b * 64 * 3136 + y * 56;
  for (int i = threadIdx.x; i < 3584; i += 256) {
    int c = i / 56, xx = i - c * 56;
    dst[(size_t)c * 3136 + xx] = lds[c * 57 + xx];
  }
}

// ---------------- launcher ----------------
extern "C" void kernel_launch(void* const* d_in, const int* in_sizes, int n_in,
                              void* d_out, int out_size, void* d_ws, size_t ws_size,
                              hipStream_t stream) {
  (void)in_sizes; (void)n_in; (void)ws_size; (void)out_size;
  const float* x     = (const float*)d_in[0];
  const float* dw    = (const float*)d_in[1];
  const float* pw    = (const float*)d_in[2];
  const float* gamma = (const float*)d_in[3];
  const float* beta  = (const float*)d_in[4];
  const float* mean  = (const float*)d_in[5];
  const float* var   = (const float*)d_in[6];
  const float* aggw  = (const float*)d_in[7];
  unsigned short* wsb = (unsigned short*)d_ws;
  float* out = (float*)d_out;

  bool adj[NN][NN];
  compute_adj(adj);

  int npred[NN], preds[NN][NN], nsucc[NN], ispan[NN], level[NN];
  for (int j = 0; j < NN; j++) {
    npred[j] = 0;
    for (int i = 0; i < j; i++) if (adj[i][j]) preds[j][npred[j]++] = i;
  }
  for (int i = 0; i < NN; i++) {
    nsucc[i] = 0; ispan[i] = NN;
    int mx = -1;
    for (int j = i + 1; j < NN; j++) if (adj[i][j]) { nsucc[i]++; mx = j; }
    if (nsucc[i] > 0) ispan[i] = mx;
  }
  int maxlev = 0;
  for (int j = 0; j < NN; j++) {
    int lv = 0;
    for (int p = 0; p < npred[j]; p++) {
      int cand = level[preds[j][p]] + 1;
      if (cand > lv) lv = cand;
    }
    level[j] = lv;
    if (lv > maxlev) maxlev = lv;
  }
  bool isfinal[NN]; int nf = 0;
  for (int i = 0; i < NN; i++) { isfinal[i] = (ispan[i] >= NN - 1); if (isfinal[i]) nf++; }
  int lastlvl[NN];
  for (int i = 0; i < NN; i++) {
    lastlvl[i] = -1;
    for (int j = i + 1; j < NN; j++) if (adj[i][j] && level[j] > lastlvl[i]) lastlvl[i] = level[j];
  }
  // slot allocation: every node gets a slot; FINAL slots are never freed
  // (finalize reads them); non-FINAL freed after last consumer level.
  int slot[NN]; bool used[NN];
  for (int s = 0; s < NN; s++) used[s] = false;
  for (int L = 0; L <= maxlev; L++) {
    for (int i = 0; i < NN; i++) {
      if (level[i] != L) continue;
      int s = 0; while (used[s]) s++;
      used[s] = true; slot[i] = s;
    }
    for (int i = 0; i < NN; i++)
      if (level[i] <= L && !isfinal[i] && lastlvl[i] == L)
        used[slot[i]] = false;
  }

  float inv_nf = 1.0f / (float)nf;

  for (int L = 0; L <= maxlev; L++) {
    GroupArg g; g.n = 0;
    for (int i = 0; i < NN; i++) {
      if (level[i] != L) continue;
      NodeDesc& nd = g.d[g.n++];
      nd.node = (uint8_t)i;
      nd.npred = (uint8_t)npred[i];
      nd.slot = (uint8_t)slot[i];
      nd.flags = 0;
      for (int p = 0; p < npred[i]; p++) nd.pred_slot[p] = (uint8_t)slot[preds[i][p]];
      if (g.n == 16) {
        g.n8 = 16;
        node_kernel<<<392 * g.n8, 512, 0, stream>>>(g, x, dw, pw, gamma, beta,
                                                    mean, var, aggw, wsb);
        g.n = 0;
      }
    }
    if (g.n > 0) {
      g.n8 = (g.n + 7) & ~7;   // pad to multiple of 8 -> node pinned to XCD node%8
      node_kernel<<<392 * g.n8, 512, 0, stream>>>(g, x, dw, pw, gamma, beta,
                                                  mean, var, aggw, wsb);
    }
  }

  FinalArg fa; fa.nf = 0;
  for (int i = 0; i < NN; i++) if (isfinal[i]) fa.slot[fa.nf++] = (uint8_t)slot[i];
  finalize_kernel<<<448, 256, 0, stream>>>(fa, wsb, out, inv_nf);
}

// Round 11
// 856.271 us; speedup vs baseline: 1.7086x; 1.7086x over previous
//
#include <hip/hip_runtime.h>
#include <cstdint>
#include <cstddef>

#define NN 32
#define NODE_ELEMS 1605632  // 8*56*56*64 elements per slot (NHWC); bf16 storage

typedef unsigned __int128 u128;

// ---------------- host: replicate np.random.default_rng(0).random((32,32)) < 0.25 ----
static void compute_adj(bool adj[NN][NN]) {
  uint32_t pool[4];
  uint32_t hc = 0x43b0d7e5u;
  auto hashmix = [&hc](uint32_t v) -> uint32_t {
    v ^= hc; hc *= 0x931e8875u; v *= hc; v ^= v >> 16; return v;
  };
  auto mix = [](uint32_t x, uint32_t y) -> uint32_t {
    uint32_t r = x * 0xca01f9ddu - y * 0x4973f715u; r ^= r >> 16; return r;
  };
  for (int i = 0; i < 4; i++) pool[i] = hashmix(0u);
  for (int s = 0; s < 4; s++)
    for (int d = 0; d < 4; d++)
      if (s != d) pool[d] = mix(pool[d], hashmix(pool[s]));
  uint32_t hb = 0x8b51f9ddu;
  uint32_t w[8];
  for (int k = 0; k < 8; k++) {
    uint32_t v = pool[k & 3];
    v ^= hb; hb *= 0x58f38dedu; v *= hb; v ^= v >> 16;
    w[k] = v;
  }
  uint64_t s64[4];
  for (int j = 0; j < 4; j++) s64[j] = (uint64_t)w[2 * j] | ((uint64_t)w[2 * j + 1] << 32);
  u128 initstate = ((u128)s64[0] << 64) | s64[1];
  u128 initseq   = ((u128)s64[2] << 64) | s64[3];
  const u128 MULT = ((u128)0x2360ED051FC65DA4ULL << 64) | 0x4385DF649FCCF645ULL;
  u128 state = 0;
  u128 inc = (initseq << 1) | 1;
  state = state * MULT + inc;
  state += initstate;
  state = state * MULT + inc;
  for (int i = 0; i < NN; i++)
    for (int j = 0; j < NN; j++) {
      state = state * MULT + inc;
      uint64_t hi = (uint64_t)(state >> 64), lo = (uint64_t)state;
      unsigned rot = (unsigned)(hi >> 58);
      uint64_t xr = hi ^ lo;
      uint64_t out = (xr >> rot) | (xr << ((64u - rot) & 63u));
      double dv = (double)(out >> 11) * (1.0 / 9007199254740992.0);
      adj[i][j] = (dv < 0.25);
    }
}

// ---------------- device ----------------
struct NodeDesc {
  uint8_t node, npred, slot, flags;
  uint8_t pred_slot[31];
  uint8_t pad;
};
struct GroupArg { int n; NodeDesc d[16]; };
struct FinalArg { int nf; uint8_t slot[32]; };

__device__ __forceinline__ float bf2f_lo(unsigned int w) {
  union { unsigned int u; float f; } c; c.u = w << 16; return c.f;
}
__device__ __forceinline__ float bf2f_hi(unsigned int w) {
  union { unsigned int u; float f; } c; c.u = w & 0xFFFF0000u; return c.f;
}
__device__ __forceinline__ float bf2f(unsigned short h) {
  union { unsigned int u; float f; } c; c.u = ((unsigned int)h) << 16; return c.f;
}
__device__ __forceinline__ unsigned short f2bf(float f) {
  union { float f; unsigned int u; } c; c.f = f;
  unsigned int u = c.u + 0x7FFFu + ((c.u >> 16) & 1u);  // RNE
  return (unsigned short)(u >> 16);
}

// Workspace slots are bf16 NHWC: elem(b,y,x,c) = ((b*56+y)*56+x)*64 + c.
// All math fp32; only inter-node storage is bf16.
//
// XCD mapping (R11): pin chunk (node, image b) to XCD (node+b)&7 via
// lin = ((j*n + k)<<3) | xcd. R10 pinned whole NODES to XCDs -> levels with
// <8 nodes starved most of the chip (2-node level = 64 CUs busy, 192 idle).
// Per-(node,b) chunks keep R10's locality win (chunk working set = np preds
// x 0.4 MB image slice ~= 3.2 MB, fits one 4 MB L2; FETCH fell 1.4 GB ->
// 252 MB) while every launch spans all 8 XCDs even for 1-node levels.
__global__ __launch_bounds__(512) void node_kernel(
    GroupArg g,
    const float* __restrict__ x,
    const float* __restrict__ dwall,
    const float* __restrict__ pwall,
    const float* __restrict__ gmall,
    const float* __restrict__ btall,
    const float* __restrict__ mnall,
    const float* __restrict__ vrall,
    const float* __restrict__ aggw,
    unsigned short* __restrict__ wsb)   // bf16 slots
{
  __shared__ float smem[6400];   // halo [100 pos][64 c]; reused as t[64 pos][64 c]
  __shared__ float pwb[4096];    // swizzled pointwise weights
  __shared__ float wlds[32];

  const int lin = blockIdx.x;
  const int xcd = lin & 7;
  const int m = lin >> 3;
  const int k = m % g.n;        // node index within group
  const int j = m / g.n;        // tile within image [0,49)
  const NodeDesc nd = g.d[k];
  const int node = nd.node;
  const int b = (xcd - node) & 7;   // image pinned so (node+b)%8 == xcd
  const int t = threadIdx.x;
  const int ty = (j / 7) * 8;
  const int tx = (j % 7) * 8;

  // stage pw weights quad-swizzled: (o,c) -> o*64 + (((c>>2)^((o>>2)&15))<<2)|(c&3)
  {
    const float* pwn = pwall + node * 4096;
    #pragma unroll
    for (int i = 0; i < 8; i++) {
      int gidx = t + 512 * i;
      int o = gidx >> 6, cc = gidx & 63;
      pwb[o * 64 + ((((cc >> 2) ^ ((o >> 2) & 15)) << 2) | (cc & 3))] = pwn[gidx];
    }
  }

  int dwc, pbase;   // depthwise ownership: channel + first of 8 positions
  if (nd.npred == 0) { dwc = t >> 3; pbase = (t & 7) * 8; }   // NCHW x gather layout
  else               { dwc = t & 63; pbase = (t >> 6) * 8; }  // NHWC halo layout

  const float* k9 = dwall + (node * 64 + dwc) * 9;
  float kk[9];
  #pragma unroll
  for (int q = 0; q < 9; q++) kk[q] = k9[q];

  float tv[8];

  if (nd.npred == 0) {
    // input node: depthwise stride-2 over relu(x), x is NCHW [8][64][112][112] fp32
    const float* xb = x + (size_t)(b * 64 + dwc) * 12544;
    #pragma unroll
    for (int jj = 0; jj < 8; jj++) {
      int p = pbase + jj;
      int oy = ty + (p >> 3), ox = tx + (p & 7);
      int iy0 = oy * 2 - 1, ix0 = ox * 2 - 1;
      float s = 0.f;
      #pragma unroll
      for (int dy = 0; dy < 3; dy++) {
        int iy = iy0 + dy;
        if ((unsigned)iy >= 112u) continue;
        const float* row = xb + iy * 112;
        #pragma unroll
        for (int dx = 0; dx < 3; dx++) {
          int ix = ix0 + dx;
          if ((unsigned)ix >= 112u) continue;
          s += fmaxf(row[ix], 0.f) * kk[dy * 3 + dx];
        }
      }
      tv[jj] = s;
    }
    __syncthreads();  // match else-branch barrier count (wlds)
    __syncthreads();  // (halo build)
    __syncthreads();  // (halo consume)
  } else {
    // sigmoid weights only for >=2 preds (single pred = pass-through)
    if (t < nd.npred) {
      float wv = 1.f / (1.f + expf(-aggw[node * 32 + t]));
      wlds[t] = (nd.npred == 1) ? 1.0f : wv;
    }
    __syncthreads();
    const int np = nd.npred;
    // aggregate + relu into fp32 NHWC halo from bf16 slots.
    // 800 units of 8 channels (16 B); thread owns unit t and 512+t (t<288);
    // 2 independent acc chains -> 2*np loads in flight.
    {
      float sa[2][8];
      int off[2];
      bool inb[2];
      #pragma unroll
      for (int u = 0; u < 2; u++) {
        int idx = t + u * 512;
        bool valid = (u == 0) || (t < 288);
        int pos = idx >> 3, q8 = idx & 7;
        int hy = pos / 10, hx = pos - hy * 10;
        int gy = ty + hy - 1, gx = tx + hx - 1;
        inb[u] = valid && ((unsigned)gy < 56u) && ((unsigned)gx < 56u);
        off[u] = ((b * 56 + gy) * 56 + gx) * 64 + q8 * 8;
        #pragma unroll
        for (int q = 0; q < 8; q++) sa[u][q] = 0.f;
      }
      for (int p = 0; p < np; p++) {
        const unsigned short* pb = wsb + (size_t)nd.pred_slot[p] * NODE_ELEMS;
        float wv = wlds[p];
        #pragma unroll
        for (int u = 0; u < 2; u++) {
          if (inb[u]) {
            uint4 v = *(const uint4*)(pb + off[u]);
            sa[u][0] = fmaf(wv, bf2f_lo(v.x), sa[u][0]);
            sa[u][1] = fmaf(wv, bf2f_hi(v.x), sa[u][1]);
            sa[u][2] = fmaf(wv, bf2f_lo(v.y), sa[u][2]);
            sa[u][3] = fmaf(wv, bf2f_hi(v.y), sa[u][3]);
            sa[u][4] = fmaf(wv, bf2f_lo(v.z), sa[u][4]);
            sa[u][5] = fmaf(wv, bf2f_hi(v.z), sa[u][5]);
            sa[u][6] = fmaf(wv, bf2f_lo(v.w), sa[u][6]);
            sa[u][7] = fmaf(wv, bf2f_hi(v.w), sa[u][7]);
          }
        }
      }
      #pragma unroll
      for (int u = 0; u < 2; u++) {
        int idx = t + u * 512;
        if ((u == 0) || (t < 288)) {
          float4 s0 = make_float4(fmaxf(sa[u][0], 0.f), fmaxf(sa[u][1], 0.f),
                                  fmaxf(sa[u][2], 0.f), fmaxf(sa[u][3], 0.f));
          float4 s1 = make_float4(fmaxf(sa[u][4], 0.f), fmaxf(sa[u][5], 0.f),
                                  fmaxf(sa[u][6], 0.f), fmaxf(sa[u][7], 0.f));
          *(float4*)&smem[idx * 8] = s0;
          *(float4*)&smem[idx * 8 + 4] = s1;
        }
      }
    }
    __syncthreads();
    // depthwise 3x3 from NHWC halo: lane = channel -> conflict-free
    #pragma unroll
    for (int jj = 0; jj < 8; jj++) {
      int p = pbase + jj;
      int py = p >> 3, px = p & 7;
      const float* r0 = smem + (py * 10 + px) * 64 + dwc;
      tv[jj] = r0[0]    * kk[0] + r0[64]   * kk[1] + r0[128]  * kk[2]
             + r0[640]  * kk[3] + r0[704]  * kk[4] + r0[768]  * kk[5]
             + r0[1280] * kk[6] + r0[1344] * kk[7] + r0[1408] * kk[8];
    }
    __syncthreads();  // halo reads done; smem re-purposed as t matrix
  }

  // t matrix t[p][c] quad-swizzled: quad' = (c>>2) ^ ((p>>2)&15)
  #pragma unroll
  for (int jj = 0; jj < 8; jj++) {
    int p = pbase + jj;
    smem[p * 64 + (((((dwc >> 2) ^ ((p >> 2) & 15))) << 2) | (dwc & 3))] = tv[jj];
  }
  __syncthreads();

  // pointwise 64x64: 4 out-channels x 2 positions per thread (8 acc)
  const int oq = t & 15;          // out-channel quad selector
  const int pgrp = t >> 4;        // position pair selector [0,32)
  const int o0 = oq << 2;
  const int p0 = pgrp << 1;
  const int bswz = (pgrp >> 1) & 15;   // (p>>2) for both p0 and p0+1
  float acc[2][4] = {};           // [pj][oi]
  #pragma unroll 4
  for (int k4 = 0; k4 < 16; k4++) {
    float4 A[4], B[2];
    #pragma unroll
    for (int oi = 0; oi < 4; oi++)
      A[oi] = *(const float4*)&pwb[(o0 + oi) * 64 + ((k4 ^ oq) << 2)];
    #pragma unroll
    for (int pj = 0; pj < 2; pj++)
      B[pj] = *(const float4*)&smem[(p0 + pj) * 64 + ((k4 ^ bswz) << 2)];
    #pragma unroll
    for (int pj = 0; pj < 2; pj++) {
      #pragma unroll
      for (int oi = 0; oi < 4; oi++) {
        acc[pj][oi] = fmaf(A[oi].x, B[pj].x, acc[pj][oi]);
        acc[pj][oi] = fmaf(A[oi].y, B[pj].y, acc[pj][oi]);
        acc[pj][oi] = fmaf(A[oi].z, B[pj].z, acc[pj][oi]);
        acc[pj][oi] = fmaf(A[oi].w, B[pj].w, acc[pj][oi]);
      }
    }
  }

  // BN + bf16 slot store (every node has a slot; FINAL slots persist)
  float inv[4], mn[4], bt[4];
  #pragma unroll
  for (int oi = 0; oi < 4; oi++) {
    int gi = node * 64 + o0 + oi;
    inv[oi] = gmall[gi] / sqrtf(vrall[gi] + 1e-5f);
    mn[oi] = mnall[gi];
    bt[oi] = btall[gi];
  }
  unsigned short* slotp = wsb + (size_t)nd.slot * NODE_ELEMS;
  #pragma unroll
  for (int pj = 0; pj < 2; pj++) {
    int p = p0 + pj;
    int gy = ty + (p >> 3), gx = tx + (p & 7);
    size_t base = (((size_t)(b * 56 + gy)) * 56 + gx) * 64 + o0;
    ushort4 h;
    h.x = f2bf((acc[pj][0] - mn[0]) * inv[0] + bt[0]);
    h.y = f2bf((acc[pj][1] - mn[1]) * inv[1] + bt[1]);
    h.z = f2bf((acc[pj][2] - mn[2]) * inv[2] + bt[2]);
    h.w = f2bf((acc[pj][3] - mn[3]) * inv[3] + bt[3]);
    *(ushort4*)&slotp[base] = h;
  }
}

// Mean of FINAL bf16 slots (fp32 accumulate) -> NCHW d_out. Block per (b,y) row.
__global__ __launch_bounds__(256) void finalize_kernel(
    FinalArg fa, const unsigned short* __restrict__ wsb,
    float* __restrict__ out, float inv_nf)
{
  __shared__ float lds[57 * 64];
  int by = blockIdx.x;
  int b = by / 56, y = by - b * 56;
  size_t rbase = (((size_t)b * 56 + y) * 56) * 64;  // [x][c]
  for (int i = threadIdx.x; i < 3584; i += 256) {
    float s = 0.f;
    for (int f = 0; f < fa.nf; f++)
      s += bf2f(wsb[(size_t)fa.slot[f] * NODE_ELEMS + rbase + i]);
    int xx = i >> 6, c = i & 63;
    lds[c * 57 + xx] = s * inv_nf;
  }
  __syncthreads();
  float* dst = out + (size_t)b * 64 * 3136 + y * 56;
  for (int i = threadIdx.x; i < 3584; i += 256) {
    int c = i / 56, xx = i - c * 56;
    dst[(size_t)c * 3136 + xx] = lds[c * 57 + xx];
  }
}

// ---------------- launcher ----------------
extern "C" void kernel_launch(void* const* d_in, const int* in_sizes, int n_in,
                              void* d_out, int out_size, void* d_ws, size_t ws_size,
                              hipStream_t stream) {
  (void)in_sizes; (void)n_in; (void)ws_size; (void)out_size;
  const float* x     = (const float*)d_in[0];
  const float* dw    = (const float*)d_in[1];
  const float* pw    = (const float*)d_in[2];
  const float* gamma = (const float*)d_in[3];
  const float* beta  = (const float*)d_in[4];
  const float* mean  = (const float*)d_in[5];
  const float* var   = (const float*)d_in[6];
  const float* aggw  = (const float*)d_in[7];
  unsigned short* wsb = (unsigned short*)d_ws;
  float* out = (float*)d_out;

  bool adj[NN][NN];
  compute_adj(adj);

  int npred[NN], preds[NN][NN], nsucc[NN], ispan[NN], level[NN];
  for (int j = 0; j < NN; j++) {
    npred[j] = 0;
    for (int i = 0; i < j; i++) if (adj[i][j]) preds[j][npred[j]++] = i;
  }
  for (int i = 0; i < NN; i++) {
    nsucc[i] = 0; ispan[i] = NN;
    int mx = -1;
    for (int j = i + 1; j < NN; j++) if (adj[i][j]) { nsucc[i]++; mx = j; }
    if (nsucc[i] > 0) ispan[i] = mx;
  }
  int maxlev = 0;
  for (int j = 0; j < NN; j++) {
    int lv = 0;
    for (int p = 0; p < npred[j]; p++) {
      int cand = level[preds[j][p]] + 1;
      if (cand > lv) lv = cand;
    }
    level[j] = lv;
    if (lv > maxlev) maxlev = lv;
  }
  bool isfinal[NN]; int nf = 0;
  for (int i = 0; i < NN; i++) { isfinal[i] = (ispan[i] >= NN - 1); if (isfinal[i]) nf++; }
  int lastlvl[NN];
  for (int i = 0; i < NN; i++) {
    lastlvl[i] = -1;
    for (int j = i + 1; j < NN; j++) if (adj[i][j] && level[j] > lastlvl[i]) lastlvl[i] = level[j];
  }
  // slot allocation: every node gets a slot; FINAL slots never freed.
  int slot[NN]; bool used[NN];
  for (int s = 0; s < NN; s++) used[s] = false;
  for (int L = 0; L <= maxlev; L++) {
    for (int i = 0; i < NN; i++) {
      if (level[i] != L) continue;
      int s = 0; while (used[s]) s++;
      used[s] = true; slot[i] = s;
    }
    for (int i = 0; i < NN; i++)
      if (level[i] <= L && !isfinal[i] && lastlvl[i] == L)
        used[slot[i]] = false;
  }

  float inv_nf = 1.0f / (float)nf;

  for (int L = 0; L <= maxlev; L++) {
    GroupArg g; g.n = 0;
    for (int i = 0; i < NN; i++) {
      if (level[i] != L) continue;
      NodeDesc& nd = g.d[g.n++];
      nd.node = (uint8_t)i;
      nd.npred = (uint8_t)npred[i];
      nd.slot = (uint8_t)slot[i];
      nd.flags = 0;
      for (int p = 0; p < npred[i]; p++) nd.pred_slot[p] = (uint8_t)slot[preds[i][p]];
      if (g.n == 16) {
        node_kernel<<<392 * g.n, 512, 0, stream>>>(g, x, dw, pw, gamma, beta,
                                                   mean, var, aggw, wsb);
        g.n = 0;
      }
    }
    if (g.n > 0) {
      node_kernel<<<392 * g.n, 512, 0, stream>>>(g, x, dw, pw, gamma, beta,
                                                 mean, var, aggw, wsb);
    }
  }

  FinalArg fa; fa.nf = 0;
  for (int i = 0; i < NN; i++) if (isfinal[i]) fa.slot[fa.nf++] = (uint8_t)slot[i];
  finalize_kernel<<<448, 256, 0, stream>>>(fa, wsb, out, inv_nf);
}

// Round 12
// 802.758 us; speedup vs baseline: 1.8225x; 1.0667x over previous
//
#include <hip/hip_runtime.h>
#include <cstdint>
#include <cstddef>

#define NN 32
#define NODE_ELEMS 1605632  // 8*56*56*64 elements per slot (NHWC); bf16 storage

typedef unsigned __int128 u128;

// ---------------- host: replicate np.random.default_rng(0).random((32,32)) < 0.25 ----
static void compute_adj(bool adj[NN][NN]) {
  uint32_t pool[4];
  uint32_t hc = 0x43b0d7e5u;
  auto hashmix = [&hc](uint32_t v) -> uint32_t {
    v ^= hc; hc *= 0x931e8875u; v *= hc; v ^= v >> 16; return v;
  };
  auto mix = [](uint32_t x, uint32_t y) -> uint32_t {
    uint32_t r = x * 0xca01f9ddu - y * 0x4973f715u; r ^= r >> 16; return r;
  };
  for (int i = 0; i < 4; i++) pool[i] = hashmix(0u);
  for (int s = 0; s < 4; s++)
    for (int d = 0; d < 4; d++)
      if (s != d) pool[d] = mix(pool[d], hashmix(pool[s]));
  uint32_t hb = 0x8b51f9ddu;
  uint32_t w[8];
  for (int k = 0; k < 8; k++) {
    uint32_t v = pool[k & 3];
    v ^= hb; hb *= 0x58f38dedu; v *= hb; v ^= v >> 16;
    w[k] = v;
  }
  uint64_t s64[4];
  for (int j = 0; j < 4; j++) s64[j] = (uint64_t)w[2 * j] | ((uint64_t)w[2 * j + 1] << 32);
  u128 initstate = ((u128)s64[0] << 64) | s64[1];
  u128 initseq   = ((u128)s64[2] << 64) | s64[3];
  const u128 MULT = ((u128)0x2360ED051FC65DA4ULL << 64) | 0x4385DF649FCCF645ULL;
  u128 state = 0;
  u128 inc = (initseq << 1) | 1;
  state = state * MULT + inc;
  state += initstate;
  state = state * MULT + inc;
  for (int i = 0; i < NN; i++)
    for (int j = 0; j < NN; j++) {
      state = state * MULT + inc;
      uint64_t hi = (uint64_t)(state >> 64), lo = (uint64_t)state;
      unsigned rot = (unsigned)(hi >> 58);
      uint64_t xr = hi ^ lo;
      uint64_t out = (xr >> rot) | (xr << ((64u - rot) & 63u));
      double dv = (double)(out >> 11) * (1.0 / 9007199254740992.0);
      adj[i][j] = (dv < 0.25);
    }
}

// ---------------- device ----------------
struct NodeDesc {
  uint8_t node, npred, slot, flags;
  uint8_t pred_slot[31];
  uint8_t pad;
};
struct GroupArg { int n; NodeDesc d[16]; };
struct FinalArg { int nf; uint8_t slot[32]; };

__device__ __forceinline__ float bf2f_lo(unsigned int w) {
  union { unsigned int u; float f; } c; c.u = w << 16; return c.f;
}
__device__ __forceinline__ float bf2f_hi(unsigned int w) {
  union { unsigned int u; float f; } c; c.u = w & 0xFFFF0000u; return c.f;
}
__device__ __forceinline__ float bf2f(unsigned short h) {
  union { unsigned int u; float f; } c; c.u = ((unsigned int)h) << 16; return c.f;
}
__device__ __forceinline__ unsigned short f2bf(float f) {
  union { float f; unsigned int u; } c; c.f = f;
  unsigned int u = c.u + 0x7FFFu + ((c.u >> 16) & 1u);  // RNE
  return (unsigned short)(u >> 16);
}

// Workspace slots are bf16 NHWC: elem(b,y,x,c) = ((b*56+y)*56+x)*64 + c.
// All math fp32; only inter-node storage is bf16.
// XCD mapping: chunk (node, image b) pinned to XCD (node+b)&7 (R11: locality
// + full-chip spread; FETCH = logical ~315 MB on the heavy group).
// R12: aggregation was latency-bound (0.96 TB/s @ 2 loads in flight/thread;
// 26 outstanding x 16 B / 200 cy L2 ~= 1 TB/s -- matched). Batch 4 preds ->
// 8 independent loads in flight before any FMA waits.
__global__ __launch_bounds__(512) void node_kernel(
    GroupArg g,
    const float* __restrict__ x,
    const float* __restrict__ dwall,
    const float* __restrict__ pwall,
    const float* __restrict__ gmall,
    const float* __restrict__ btall,
    const float* __restrict__ mnall,
    const float* __restrict__ vrall,
    const float* __restrict__ aggw,
    unsigned short* __restrict__ wsb)   // bf16 slots
{
  __shared__ float smem[6400];   // halo [100 pos][64 c]; reused as t[64 pos][64 c]
  __shared__ float pwb[4096];    // swizzled pointwise weights
  __shared__ float wlds[32];

  const int lin = blockIdx.x;
  const int xcd = lin & 7;
  const int m = lin >> 3;
  const int k = m % g.n;        // node index within group
  const int j = m / g.n;        // tile within image [0,49)
  const NodeDesc nd = g.d[k];
  const int node = nd.node;
  const int b = (xcd - node) & 7;   // image pinned so (node+b)%8 == xcd
  const int t = threadIdx.x;
  const int ty = (j / 7) * 8;
  const int tx = (j % 7) * 8;

  // stage pw weights quad-swizzled: (o,c) -> o*64 + (((c>>2)^((o>>2)&15))<<2)|(c&3)
  {
    const float* pwn = pwall + node * 4096;
    #pragma unroll
    for (int i = 0; i < 8; i++) {
      int gidx = t + 512 * i;
      int o = gidx >> 6, cc = gidx & 63;
      pwb[o * 64 + ((((cc >> 2) ^ ((o >> 2) & 15)) << 2) | (cc & 3))] = pwn[gidx];
    }
  }

  int dwc, pbase;   // depthwise ownership: channel + first of 8 positions
  if (nd.npred == 0) { dwc = t >> 3; pbase = (t & 7) * 8; }   // NCHW x gather layout
  else               { dwc = t & 63; pbase = (t >> 6) * 8; }  // NHWC halo layout

  const float* k9 = dwall + (node * 64 + dwc) * 9;
  float kk[9];
  #pragma unroll
  for (int q = 0; q < 9; q++) kk[q] = k9[q];

  float tv[8];

  if (nd.npred == 0) {
    // input node: depthwise stride-2 over relu(x), x is NCHW [8][64][112][112] fp32
    const float* xb = x + (size_t)(b * 64 + dwc) * 12544;
    #pragma unroll
    for (int jj = 0; jj < 8; jj++) {
      int p = pbase + jj;
      int oy = ty + (p >> 3), ox = tx + (p & 7);
      int iy0 = oy * 2 - 1, ix0 = ox * 2 - 1;
      float s = 0.f;
      #pragma unroll
      for (int dy = 0; dy < 3; dy++) {
        int iy = iy0 + dy;
        if ((unsigned)iy >= 112u) continue;
        const float* row = xb + iy * 112;
        #pragma unroll
        for (int dx = 0; dx < 3; dx++) {
          int ix = ix0 + dx;
          if ((unsigned)ix >= 112u) continue;
          s += fmaxf(row[ix], 0.f) * kk[dy * 3 + dx];
        }
      }
      tv[jj] = s;
    }
    __syncthreads();  // match else-branch barrier count (wlds)
    __syncthreads();  // (halo build)
    __syncthreads();  // (halo consume)
  } else {
    // sigmoid weights only for >=2 preds (single pred = pass-through)
    if (t < nd.npred) {
      float wv = 1.f / (1.f + expf(-aggw[node * 32 + t]));
      wlds[t] = (nd.npred == 1) ? 1.0f : wv;
    }
    __syncthreads();
    const int np = nd.npred;
    // aggregate + relu into fp32 NHWC halo from bf16 slots.
    // 800 units of 8 channels (16 B); thread owns unit t and 512+t (t<288).
    // Preds processed in batches of 4 -> 8 independent loads in flight
    // before any dependent FMA (R11 was 2-in-flight latency-bound).
    {
      float sa[2][8];
      int off[2];
      bool inb[2];
      #pragma unroll
      for (int u = 0; u < 2; u++) {
        int idx = t + u * 512;
        bool valid = (u == 0) || (t < 288);
        int pos = idx >> 3, q8 = idx & 7;
        int hy = pos / 10, hx = pos - hy * 10;
        int gy = ty + hy - 1, gx = tx + hx - 1;
        inb[u] = valid && ((unsigned)gy < 56u) && ((unsigned)gx < 56u);
        off[u] = ((b * 56 + gy) * 56 + gx) * 64 + q8 * 8;
        #pragma unroll
        for (int q = 0; q < 8; q++) sa[u][q] = 0.f;
      }
      for (int p0 = 0; p0 < np; p0 += 4) {
        uint4 v[4][2];
        #pragma unroll
        for (int pp = 0; pp < 4; pp++) {
          if (p0 + pp < np) {
            const unsigned short* pb = wsb + (size_t)nd.pred_slot[p0 + pp] * NODE_ELEMS;
            #pragma unroll
            for (int u = 0; u < 2; u++)
              if (inb[u]) v[pp][u] = *(const uint4*)(pb + off[u]);
          }
        }
        #pragma unroll
        for (int pp = 0; pp < 4; pp++) {
          if (p0 + pp < np) {
            float wv = wlds[p0 + pp];
            #pragma unroll
            for (int u = 0; u < 2; u++) {
              if (inb[u]) {
                sa[u][0] = fmaf(wv, bf2f_lo(v[pp][u].x), sa[u][0]);
                sa[u][1] = fmaf(wv, bf2f_hi(v[pp][u].x), sa[u][1]);
                sa[u][2] = fmaf(wv, bf2f_lo(v[pp][u].y), sa[u][2]);
                sa[u][3] = fmaf(wv, bf2f_hi(v[pp][u].y), sa[u][3]);
                sa[u][4] = fmaf(wv, bf2f_lo(v[pp][u].z), sa[u][4]);
                sa[u][5] = fmaf(wv, bf2f_hi(v[pp][u].z), sa[u][5]);
                sa[u][6] = fmaf(wv, bf2f_lo(v[pp][u].w), sa[u][6]);
                sa[u][7] = fmaf(wv, bf2f_hi(v[pp][u].w), sa[u][7]);
              }
            }
          }
        }
      }
      #pragma unroll
      for (int u = 0; u < 2; u++) {
        int idx = t + u * 512;
        if ((u == 0) || (t < 288)) {
          float4 s0 = make_float4(fmaxf(sa[u][0], 0.f), fmaxf(sa[u][1], 0.f),
                                  fmaxf(sa[u][2], 0.f), fmaxf(sa[u][3], 0.f));
          float4 s1 = make_float4(fmaxf(sa[u][4], 0.f), fmaxf(sa[u][5], 0.f),
                                  fmaxf(sa[u][6], 0.f), fmaxf(sa[u][7], 0.f));
          *(float4*)&smem[idx * 8] = s0;
          *(float4*)&smem[idx * 8 + 4] = s1;
        }
      }
    }
    __syncthreads();
    // depthwise 3x3 from NHWC halo: lane = channel -> conflict-free
    #pragma unroll
    for (int jj = 0; jj < 8; jj++) {
      int p = pbase + jj;
      int py = p >> 3, px = p & 7;
      const float* r0 = smem + (py * 10 + px) * 64 + dwc;
      tv[jj] = r0[0]    * kk[0] + r0[64]   * kk[1] + r0[128]  * kk[2]
             + r0[640]  * kk[3] + r0[704]  * kk[4] + r0[768]  * kk[5]
             + r0[1280] * kk[6] + r0[1344] * kk[7] + r0[1408] * kk[8];
    }
    __syncthreads();  // halo reads done; smem re-purposed as t matrix
  }

  // t matrix t[p][c] quad-swizzled: quad' = (c>>2) ^ ((p>>2)&15)
  #pragma unroll
  for (int jj = 0; jj < 8; jj++) {
    int p = pbase + jj;
    smem[p * 64 + (((((dwc >> 2) ^ ((p >> 2) & 15))) << 2) | (dwc & 3))] = tv[jj];
  }
  __syncthreads();

  // pointwise 64x64: 4 out-channels x 2 positions per thread (8 acc)
  const int oq = t & 15;          // out-channel quad selector
  const int pgrp = t >> 4;        // position pair selector [0,32)
  const int o0 = oq << 2;
  const int p0 = pgrp << 1;
  const int bswz = (pgrp >> 1) & 15;   // (p>>2) for both p0 and p0+1
  float acc[2][4] = {};           // [pj][oi]
  #pragma unroll 4
  for (int k4 = 0; k4 < 16; k4++) {
    float4 A[4], B[2];
    #pragma unroll
    for (int oi = 0; oi < 4; oi++)
      A[oi] = *(const float4*)&pwb[(o0 + oi) * 64 + ((k4 ^ oq) << 2)];
    #pragma unroll
    for (int pj = 0; pj < 2; pj++)
      B[pj] = *(const float4*)&smem[(p0 + pj) * 64 + ((k4 ^ bswz) << 2)];
    #pragma unroll
    for (int pj = 0; pj < 2; pj++) {
      #pragma unroll
      for (int oi = 0; oi < 4; oi++) {
        acc[pj][oi] = fmaf(A[oi].x, B[pj].x, acc[pj][oi]);
        acc[pj][oi] = fmaf(A[oi].y, B[pj].y, acc[pj][oi]);
        acc[pj][oi] = fmaf(A[oi].z, B[pj].z, acc[pj][oi]);
        acc[pj][oi] = fmaf(A[oi].w, B[pj].w, acc[pj][oi]);
      }
    }
  }

  // BN + bf16 slot store (every node has a slot; FINAL slots persist)
  float inv[4], mn[4], bt[4];
  #pragma unroll
  for (int oi = 0; oi < 4; oi++) {
    int gi = node * 64 + o0 + oi;
    inv[oi] = gmall[gi] / sqrtf(vrall[gi] + 1e-5f);
    mn[oi] = mnall[gi];
    bt[oi] = btall[gi];
  }
  unsigned short* slotp = wsb + (size_t)nd.slot * NODE_ELEMS;
  #pragma unroll
  for (int pj = 0; pj < 2; pj++) {
    int p = p0 + pj;
    int gy = ty + (p >> 3), gx = tx + (p & 7);
    size_t base = (((size_t)(b * 56 + gy)) * 56 + gx) * 64 + o0;
    ushort4 h;
    h.x = f2bf((acc[pj][0] - mn[0]) * inv[0] + bt[0]);
    h.y = f2bf((acc[pj][1] - mn[1]) * inv[1] + bt[1]);
    h.z = f2bf((acc[pj][2] - mn[2]) * inv[2] + bt[2]);
    h.w = f2bf((acc[pj][3] - mn[3]) * inv[3] + bt[3]);
    *(ushort4*)&slotp[base] = h;
  }
}

// Mean of FINAL bf16 slots (fp32 accumulate) -> NCHW d_out. Block per (b,y) row.
__global__ __launch_bounds__(256) void finalize_kernel(
    FinalArg fa, const unsigned short* __restrict__ wsb,
    float* __restrict__ out, float inv_nf)
{
  __shared__ float lds[57 * 64];
  int by = blockIdx.x;
  int b = by / 56, y = by - b * 56;
  size_t rbase = (((size_t)b * 56 + y) * 56) * 64;  // [x][c]
  for (int i = threadIdx.x; i < 3584; i += 256) {
    float s = 0.f;
    for (int f = 0; f < fa.nf; f++)
      s += bf2f(wsb[(size_t)fa.slot[f] * NODE_ELEMS + rbase + i]);
    int xx = i >> 6, c = i & 63;
    lds[c * 57 + xx] = s * inv_nf;
  }
  __syncthreads();
  float* dst = out + (size_t)b * 64 * 3136 + y * 56;
  for (int i = threadIdx.x; i < 3584; i += 256) {
    int c = i / 56, xx = i - c * 56;
    dst[(size_t)c * 3136 + xx] = lds[c * 57 + xx];
  }
}

// ---------------- launcher ----------------
extern "C" void kernel_launch(void* const* d_in, const int* in_sizes, int n_in,
                              void* d_out, int out_size, void* d_ws, size_t ws_size,
                              hipStream_t stream) {
  (void)in_sizes; (void)n_in; (void)ws_size; (void)out_size;
  const float* x     = (const float*)d_in[0];
  const float* dw    = (const float*)d_in[1];
  const float* pw    = (const float*)d_in[2];
  const float* gamma = (const float*)d_in[3];
  const float* beta  = (const float*)d_in[4];
  const float* mean  = (const float*)d_in[5];
  const float* var   = (const float*)d_in[6];
  const float* aggw  = (const float*)d_in[7];
  unsigned short* wsb = (unsigned short*)d_ws;
  float* out = (float*)d_out;

  bool adj[NN][NN];
  compute_adj(adj);

  int npred[NN], preds[NN][NN], nsucc[NN], ispan[NN], level[NN];
  for (int j = 0; j < NN; j++) {
    npred[j] = 0;
    for (int i = 0; i < j; i++) if (adj[i][j]) preds[j][npred[j]++] = i;
  }
  for (int i = 0; i < NN; i++) {
    nsucc[i] = 0; ispan[i] = NN;
    int mx = -1;
    for (int j = i + 1; j < NN; j++) if (adj[i][j]) { nsucc[i]++; mx = j; }
    if (nsucc[i] > 0) ispan[i] = mx;
  }
  int maxlev = 0;
  for (int j = 0; j < NN; j++) {
    int lv = 0;
    for (int p = 0; p < npred[j]; p++) {
      int cand = level[preds[j][p]] + 1;
      if (cand > lv) lv = cand;
    }
    level[j] = lv;
    if (lv > maxlev) maxlev = lv;
  }
  bool isfinal[NN]; int nf = 0;
  for (int i = 0; i < NN; i++) { isfinal[i] = (ispan[i] >= NN - 1); if (isfinal[i]) nf++; }
  int lastlvl[NN];
  for (int i = 0; i < NN; i++) {
    lastlvl[i] = -1;
    for (int j = i + 1; j < NN; j++) if (adj[i][j] && level[j] > lastlvl[i]) lastlvl[i] = level[j];
  }
  // slot allocation: every node gets a slot; FINAL slots never freed.
  int slot[NN]; bool used[NN];
  for (int s = 0; s < NN; s++) used[s] = false;
  for (int L = 0; L <= maxlev; L++) {
    for (int i = 0; i < NN; i++) {
      if (level[i] != L) continue;
      int s = 0; while (used[s]) s++;
      used[s] = true; slot[i] = s;
    }
    for (int i = 0; i < NN; i++)
      if (level[i] <= L && !isfinal[i] && lastlvl[i] == L)
        used[slot[i]] = false;
  }

  float inv_nf = 1.0f / (float)nf;

  for (int L = 0; L <= maxlev; L++) {
    GroupArg g; g.n = 0;
    for (int i = 0; i < NN; i++) {
      if (level[i] != L) continue;
      NodeDesc& nd = g.d[g.n++];
      nd.node = (uint8_t)i;
      nd.npred = (uint8_t)npred[i];
      nd.slot = (uint8_t)slot[i];
      nd.flags = 0;
      for (int p = 0; p < npred[i]; p++) nd.pred_slot[p] = (uint8_t)slot[preds[i][p]];
      if (g.n == 16) {
        node_kernel<<<392 * g.n, 512, 0, stream>>>(g, x, dw, pw, gamma, beta,
                                                   mean, var, aggw, wsb);
        g.n = 0;
      }
    }
    if (g.n > 0) {
      node_kernel<<<392 * g.n, 512, 0, stream>>>(g, x, dw, pw, gamma, beta,
                                                 mean, var, aggw, wsb);
    }
  }

  FinalArg fa; fa.nf = 0;
  for (int i = 0; i < NN; i++) if (isfinal[i]) fa.slot[fa.nf++] = (uint8_t)slot[i];
  finalize_kernel<<<448, 256, 0, stream>>>(fa, wsb, out, inv_nf);
}

// Round 13
// 786.310 us; speedup vs baseline: 1.8606x; 1.0209x over previous
//
#include <hip/hip_runtime.h>
#include <cstdint>
#include <cstddef>

#define NN 32
#define NODE_ELEMS 1605632  // 8*56*56*64 elements per slot (NHWC); bf16 storage

typedef unsigned __int128 u128;

// ---------------- host: replicate np.random.default_rng(0).random((32,32)) < 0.25 ----
static void compute_adj(bool adj[NN][NN]) {
  uint32_t pool[4];
  uint32_t hc = 0x43b0d7e5u;
  auto hashmix = [&hc](uint32_t v) -> uint32_t {
    v ^= hc; hc *= 0x931e8875u; v *= hc; v ^= v >> 16; return v;
  };
  auto mix = [](uint32_t x, uint32_t y) -> uint32_t {
    uint32_t r = x * 0xca01f9ddu - y * 0x4973f715u; r ^= r >> 16; return r;
  };
  for (int i = 0; i < 4; i++) pool[i] = hashmix(0u);
  for (int s = 0; s < 4; s++)
    for (int d = 0; d < 4; d++)
      if (s != d) pool[d] = mix(pool[d], hashmix(pool[s]));
  uint32_t hb = 0x8b51f9ddu;
  uint32_t w[8];
  for (int k = 0; k < 8; k++) {
    uint32_t v = pool[k & 3];
    v ^= hb; hb *= 0x58f38dedu; v *= hb; v ^= v >> 16;
    w[k] = v;
  }
  uint64_t s64[4];
  for (int j = 0; j < 4; j++) s64[j] = (uint64_t)w[2 * j] | ((uint64_t)w[2 * j + 1] << 32);
  u128 initstate = ((u128)s64[0] << 64) | s64[1];
  u128 initseq   = ((u128)s64[2] << 64) | s64[3];
  const u128 MULT = ((u128)0x2360ED051FC65DA4ULL << 64) | 0x4385DF649FCCF645ULL;
  u128 state = 0;
  u128 inc = (initseq << 1) | 1;
  state = state * MULT + inc;
  state += initstate;
  state = state * MULT + inc;
  for (int i = 0; i < NN; i++)
    for (int j = 0; j < NN; j++) {
      state = state * MULT + inc;
      uint64_t hi = (uint64_t)(state >> 64), lo = (uint64_t)state;
      unsigned rot = (unsigned)(hi >> 58);
      uint64_t xr = hi ^ lo;
      uint64_t out = (xr >> rot) | (xr << ((64u - rot) & 63u));
      double dv = (double)(out >> 11) * (1.0 / 9007199254740992.0);
      adj[i][j] = (dv < 0.25);
    }
}

// ---------------- device ----------------
struct NodeDesc {
  uint8_t node, npred, slot, flags;
  uint8_t pred_slot[31];
  uint8_t pad;
};
struct GroupArg { int n; NodeDesc d[16]; };
struct FinalArg { int nf; uint8_t slot[32]; };

__device__ __forceinline__ float bf2f_lo(unsigned int w) {
  union { unsigned int u; float f; } c; c.u = w << 16; return c.f;
}
__device__ __forceinline__ float bf2f_hi(unsigned int w) {
  union { unsigned int u; float f; } c; c.u = w & 0xFFFF0000u; return c.f;
}
__device__ __forceinline__ float bf2f(unsigned short h) {
  union { unsigned int u; float f; } c; c.u = ((unsigned int)h) << 16; return c.f;
}
__device__ __forceinline__ unsigned short f2bf(float f) {
  union { float f; unsigned int u; } c; c.f = f;
  unsigned int u = c.u + 0x7FFFu + ((c.u >> 16) & 1u);  // RNE
  return (unsigned short)(u >> 16);
}

// Workspace slots are bf16 NHWC: elem(b,y,x,c) = ((b*56+y)*56+x)*64 + c.
// All math fp32; only inter-node storage is bf16.
// XCD mapping: chunk (node, image b) pinned to XCD (node+b)&7.
// R13: block order within an XCD is now CHUNK-CONTIGUOUS: lin = ((k*49+j)<<3)|xcd
// with tile j fastest. R12 had node k fastest -> consecutive blocks on one XCD
// alternated between different nodes' chunks, L2 juggled n x 3.2 MB working
// sets (> 4 MB) and thrashed: FETCH 264 MB vs ~110 MB unique footprint, all
// halo/shared-pred reuse lost. j-fastest keeps ~one chunk (np x 0.4 MB) hot.
__global__ __launch_bounds__(512) void node_kernel(
    GroupArg g,
    const float* __restrict__ x,
    const float* __restrict__ dwall,
    const float* __restrict__ pwall,
    const float* __restrict__ gmall,
    const float* __restrict__ btall,
    const float* __restrict__ mnall,
    const float* __restrict__ vrall,
    const float* __restrict__ aggw,
    unsigned short* __restrict__ wsb)   // bf16 slots
{
  __shared__ float smem[6400];   // halo [100 pos][64 c]; reused as t[64 pos][64 c]
  __shared__ float pwb[4096];    // swizzled pointwise weights
  __shared__ float wlds[32];

  const int lin = blockIdx.x;
  const int xcd = lin & 7;
  const int m = lin >> 3;
  const int k = m / 49;         // node index within group (slow)
  const int j = m - k * 49;     // tile within image [0,49) (fast -> L2 locality)
  const NodeDesc nd = g.d[k];
  const int node = nd.node;
  const int b = (xcd - node) & 7;   // image pinned so (node+b)%8 == xcd
  const int t = threadIdx.x;
  const int ty = (j / 7) * 8;
  const int tx = (j % 7) * 8;

  // stage pw weights quad-swizzled: (o,c) -> o*64 + (((c>>2)^((o>>2)&15))<<2)|(c&3)
  {
    const float* pwn = pwall + node * 4096;
    #pragma unroll
    for (int i = 0; i < 8; i++) {
      int gidx = t + 512 * i;
      int o = gidx >> 6, cc = gidx & 63;
      pwb[o * 64 + ((((cc >> 2) ^ ((o >> 2) & 15)) << 2) | (cc & 3))] = pwn[gidx];
    }
  }

  int dwc, pbase;   // depthwise ownership: channel + first of 8 positions
  if (nd.npred == 0) { dwc = t >> 3; pbase = (t & 7) * 8; }   // NCHW x gather layout
  else               { dwc = t & 63; pbase = (t >> 6) * 8; }  // NHWC halo layout

  const float* k9 = dwall + (node * 64 + dwc) * 9;
  float kk[9];
  #pragma unroll
  for (int q = 0; q < 9; q++) kk[q] = k9[q];

  float tv[8];

  if (nd.npred == 0) {
    // input node: depthwise stride-2 over relu(x), x is NCHW [8][64][112][112] fp32
    const float* xb = x + (size_t)(b * 64 + dwc) * 12544;
    #pragma unroll
    for (int jj = 0; jj < 8; jj++) {
      int p = pbase + jj;
      int oy = ty + (p >> 3), ox = tx + (p & 7);
      int iy0 = oy * 2 - 1, ix0 = ox * 2 - 1;
      float s = 0.f;
      #pragma unroll
      for (int dy = 0; dy < 3; dy++) {
        int iy = iy0 + dy;
        if ((unsigned)iy >= 112u) continue;
        const float* row = xb + iy * 112;
        #pragma unroll
        for (int dx = 0; dx < 3; dx++) {
          int ix = ix0 + dx;
          if ((unsigned)ix >= 112u) continue;
          s += fmaxf(row[ix], 0.f) * kk[dy * 3 + dx];
        }
      }
      tv[jj] = s;
    }
    __syncthreads();  // match else-branch barrier count (wlds)
    __syncthreads();  // (halo build)
    __syncthreads();  // (halo consume)
  } else {
    // sigmoid weights only for >=2 preds (single pred = pass-through)
    if (t < nd.npred) {
      float wv = 1.f / (1.f + expf(-aggw[node * 32 + t]));
      wlds[t] = (nd.npred == 1) ? 1.0f : wv;
    }
    __syncthreads();
    const int np = nd.npred;
    // aggregate + relu into fp32 NHWC halo from bf16 slots.
    // 800 units of 8 channels (16 B); thread owns unit t and 512+t (t<288).
    // Preds in batches of 4 -> 8 independent loads in flight per thread.
    {
      float sa[2][8];
      int off[2];
      bool inb[2];
      #pragma unroll
      for (int u = 0; u < 2; u++) {
        int idx = t + u * 512;
        bool valid = (u == 0) || (t < 288);
        int pos = idx >> 3, q8 = idx & 7;
        int hy = pos / 10, hx = pos - hy * 10;
        int gy = ty + hy - 1, gx = tx + hx - 1;
        inb[u] = valid && ((unsigned)gy < 56u) && ((unsigned)gx < 56u);
        off[u] = ((b * 56 + gy) * 56 + gx) * 64 + q8 * 8;
        #pragma unroll
        for (int q = 0; q < 8; q++) sa[u][q] = 0.f;
      }
      for (int p0 = 0; p0 < np; p0 += 4) {
        uint4 v[4][2];
        #pragma unroll
        for (int pp = 0; pp < 4; pp++) {
          if (p0 + pp < np) {
            const unsigned short* pb = wsb + (size_t)nd.pred_slot[p0 + pp] * NODE_ELEMS;
            #pragma unroll
            for (int u = 0; u < 2; u++)
              if (inb[u]) v[pp][u] = *(const uint4*)(pb + off[u]);
          }
        }
        #pragma unroll
        for (int pp = 0; pp < 4; pp++) {
          if (p0 + pp < np) {
            float wv = wlds[p0 + pp];
            #pragma unroll
            for (int u = 0; u < 2; u++) {
              if (inb[u]) {
                sa[u][0] = fmaf(wv, bf2f_lo(v[pp][u].x), sa[u][0]);
                sa[u][1] = fmaf(wv, bf2f_hi(v[pp][u].x), sa[u][1]);
                sa[u][2] = fmaf(wv, bf2f_lo(v[pp][u].y), sa[u][2]);
                sa[u][3] = fmaf(wv, bf2f_hi(v[pp][u].y), sa[u][3]);
                sa[u][4] = fmaf(wv, bf2f_lo(v[pp][u].z), sa[u][4]);
                sa[u][5] = fmaf(wv, bf2f_hi(v[pp][u].z), sa[u][5]);
                sa[u][6] = fmaf(wv, bf2f_lo(v[pp][u].w), sa[u][6]);
                sa[u][7] = fmaf(wv, bf2f_hi(v[pp][u].w), sa[u][7]);
              }
            }
          }
        }
      }
      #pragma unroll
      for (int u = 0; u < 2; u++) {
        int idx = t + u * 512;
        if ((u == 0) || (t < 288)) {
          float4 s0 = make_float4(fmaxf(sa[u][0], 0.f), fmaxf(sa[u][1], 0.f),
                                  fmaxf(sa[u][2], 0.f), fmaxf(sa[u][3], 0.f));
          float4 s1 = make_float4(fmaxf(sa[u][4], 0.f), fmaxf(sa[u][5], 0.f),
                                  fmaxf(sa[u][6], 0.f), fmaxf(sa[u][7], 0.f));
          *(float4*)&smem[idx * 8] = s0;
          *(float4*)&smem[idx * 8 + 4] = s1;
        }
      }
    }
    __syncthreads();
    // depthwise 3x3 from NHWC halo: lane = channel -> conflict-free
    #pragma unroll
    for (int jj = 0; jj < 8; jj++) {
      int p = pbase + jj;
      int py = p >> 3, px = p & 7;
      const float* r0 = smem + (py * 10 + px) * 64 + dwc;
      tv[jj] = r0[0]    * kk[0] + r0[64]   * kk[1] + r0[128]  * kk[2]
             + r0[640]  * kk[3] + r0[704]  * kk[4] + r0[768]  * kk[5]
             + r0[1280] * kk[6] + r0[1344] * kk[7] + r0[1408] * kk[8];
    }
    __syncthreads();  // halo reads done; smem re-purposed as t matrix
  }

  // t matrix t[p][c] quad-swizzled: quad' = (c>>2) ^ ((p>>2)&15)
  #pragma unroll
  for (int jj = 0; jj < 8; jj++) {
    int p = pbase + jj;
    smem[p * 64 + (((((dwc >> 2) ^ ((p >> 2) & 15))) << 2) | (dwc & 3))] = tv[jj];
  }
  __syncthreads();

  // pointwise 64x64: 4 out-channels x 2 positions per thread (8 acc)
  const int oq = t & 15;          // out-channel quad selector
  const int pgrp = t >> 4;        // position pair selector [0,32)
  const int o0 = oq << 2;
  const int p0 = pgrp << 1;
  const int bswz = (pgrp >> 1) & 15;   // (p>>2) for both p0 and p0+1
  float acc[2][4] = {};           // [pj][oi]
  #pragma unroll 4
  for (int k4 = 0; k4 < 16; k4++) {
    float4 A[4], B[2];
    #pragma unroll
    for (int oi = 0; oi < 4; oi++)
      A[oi] = *(const float4*)&pwb[(o0 + oi) * 64 + ((k4 ^ oq) << 2)];
    #pragma unroll
    for (int pj = 0; pj < 2; pj++)
      B[pj] = *(const float4*)&smem[(p0 + pj) * 64 + ((k4 ^ bswz) << 2)];
    #pragma unroll
    for (int pj = 0; pj < 2; pj++) {
      #pragma unroll
      for (int oi = 0; oi < 4; oi++) {
        acc[pj][oi] = fmaf(A[oi].x, B[pj].x, acc[pj][oi]);
        acc[pj][oi] = fmaf(A[oi].y, B[pj].y, acc[pj][oi]);
        acc[pj][oi] = fmaf(A[oi].z, B[pj].z, acc[pj][oi]);
        acc[pj][oi] = fmaf(A[oi].w, B[pj].w, acc[pj][oi]);
      }
    }
  }

  // BN + bf16 slot store (every node has a slot; FINAL slots persist)
  float inv[4], mn[4], bt[4];
  #pragma unroll
  for (int oi = 0; oi < 4; oi++) {
    int gi = node * 64 + o0 + oi;
    inv[oi] = gmall[gi] / sqrtf(vrall[gi] + 1e-5f);
    mn[oi] = mnall[gi];
    bt[oi] = btall[gi];
  }
  unsigned short* slotp = wsb + (size_t)nd.slot * NODE_ELEMS;
  #pragma unroll
  for (int pj = 0; pj < 2; pj++) {
    int p = p0 + pj;
    int gy = ty + (p >> 3), gx = tx + (p & 7);
    size_t base = (((size_t)(b * 56 + gy)) * 56 + gx) * 64 + o0;
    ushort4 h;
    h.x = f2bf((acc[pj][0] - mn[0]) * inv[0] + bt[0]);
    h.y = f2bf((acc[pj][1] - mn[1]) * inv[1] + bt[1]);
    h.z = f2bf((acc[pj][2] - mn[2]) * inv[2] + bt[2]);
    h.w = f2bf((acc[pj][3] - mn[3]) * inv[3] + bt[3]);
    *(ushort4*)&slotp[base] = h;
  }
}

// Mean of FINAL bf16 slots (fp32 accumulate) -> NCHW d_out. Block per (b,y) row.
__global__ __launch_bounds__(256) void finalize_kernel(
    FinalArg fa, const unsigned short* __restrict__ wsb,
    float* __restrict__ out, float inv_nf)
{
  __shared__ float lds[57 * 64];
  int by = blockIdx.x;
  int b = by / 56, y = by - b * 56;
  size_t rbase = (((size_t)b * 56 + y) * 56) * 64;  // [x][c]
  for (int i = threadIdx.x; i < 3584; i += 256) {
    float s = 0.f;
    for (int f = 0; f < fa.nf; f++)
      s += bf2f(wsb[(size_t)fa.slot[f] * NODE_ELEMS + rbase + i]);
    int xx = i >> 6, c = i & 63;
    lds[c * 57 + xx] = s * inv_nf;
  }
  __syncthreads();
  float* dst = out + (size_t)b * 64 * 3136 + y * 56;
  for (int i = threadIdx.x; i < 3584; i += 256) {
    int c = i / 56, xx = i - c * 56;
    dst[(size_t)c * 3136 + xx] = lds[c * 57 + xx];
  }
}

// ---------------- launcher ----------------
extern "C" void kernel_launch(void* const* d_in, const int* in_sizes, int n_in,
                              void* d_out, int out_size, void* d_ws, size_t ws_size,
                              hipStream_t stream) {
  (void)in_sizes; (void)n_in; (void)ws_size; (void)out_size;
  const float* x     = (const float*)d_in[0];
  const float* dw    = (const float*)d_in[1];
  const float* pw    = (const float*)d_in[2];
  const float* gamma = (const float*)d_in[3];
  const float* beta  = (const float*)d_in[4];
  const float* mean  = (const float*)d_in[5];
  const float* var   = (const float*)d_in[6];
  const float* aggw  = (const float*)d_in[7];
  unsigned short* wsb = (unsigned short*)d_ws;
  float* out = (float*)d_out;

  bool adj[NN][NN];
  compute_adj(adj);

  int npred[NN], preds[NN][NN], nsucc[NN], ispan[NN], level[NN];
  for (int j = 0; j < NN; j++) {
    npred[j] = 0;
    for (int i = 0; i < j; i++) if (adj[i][j]) preds[j][npred[j]++] = i;
  }
  for (int i = 0; i < NN; i++) {
    nsucc[i] = 0; ispan[i] = NN;
    int mx = -1;
    for (int j = i + 1; j < NN; j++) if (adj[i][j]) { nsucc[i]++; mx = j; }
    if (nsucc[i] > 0) ispan[i] = mx;
  }
  int maxlev = 0;
  for (int j = 0; j < NN; j++) {
    int lv = 0;
    for (int p = 0; p < npred[j]; p++) {
      int cand = level[preds[j][p]] + 1;
      if (cand > lv) lv = cand;
    }
    level[j] = lv;
    if (lv > maxlev) maxlev = lv;
  }
  bool isfinal[NN]; int nf = 0;
  for (int i = 0; i < NN; i++) { isfinal[i] = (ispan[i] >= NN - 1); if (isfinal[i]) nf++; }
  int lastlvl[NN];
  for (int i = 0; i < NN; i++) {
    lastlvl[i] = -1;
    for (int j = i + 1; j < NN; j++) if (adj[i][j] && level[j] > lastlvl[i]) lastlvl[i] = level[j];
  }
  // slot allocation: every node gets a slot; FINAL slots never freed.
  int slot[NN]; bool used[NN];
  for (int s = 0; s < NN; s++) used[s] = false;
  for (int L = 0; L <= maxlev; L++) {
    for (int i = 0; i < NN; i++) {
      if (level[i] != L) continue;
      int s = 0; while (used[s]) s++;
      used[s] = true; slot[i] = s;
    }
    for (int i = 0; i < NN; i++)
      if (level[i] <= L && !isfinal[i] && lastlvl[i] == L)
        used[slot[i]] = false;
  }

  float inv_nf = 1.0f / (float)nf;

  for (int L = 0; L <= maxlev; L++) {
    GroupArg g; g.n = 0;
    for (int i = 0; i < NN; i++) {
      if (level[i] != L) continue;
      NodeDesc& nd = g.d[g.n++];
      nd.node = (uint8_t)i;
      nd.npred = (uint8_t)npred[i];
      nd.slot = (uint8_t)slot[i];
      nd.flags = 0;
      for (int p = 0; p < npred[i]; p++) nd.pred_slot[p] = (uint8_t)slot[preds[i][p]];
      if (g.n == 16) {
        node_kernel<<<392 * g.n, 512, 0, stream>>>(g, x, dw, pw, gamma, beta,
                                                   mean, var, aggw, wsb);
        g.n = 0;
      }
    }
    if (g.n > 0) {
      node_kernel<<<392 * g.n, 512, 0, stream>>>(g, x, dw, pw, gamma, beta,
                                                 mean, var, aggw, wsb);
    }
  }

  FinalArg fa; fa.nf = 0;
  for (int i = 0; i < NN; i++) if (isfinal[i]) fa.slot[fa.nf++] = (uint8_t)slot[i];
  finalize_kernel<<<448, 256, 0, stream>>>(fa, wsb, out, inv_nf);
}